// Round 19
// baseline (2930.652 us; speedup 1.0000x reference)
//
#include <hip/hip_runtime.h>

// Residual VQ — bf16-MFMA screen + np-exact rescore. Round 19: TM=64 with
// sibling-wave address sharing. r18's wall: 33.5 TB of cbf flowing through
// L2/L3 (~15 TB/s = Infinity-Cache BW class) because each 16-token block
// reads the full 512 KB codebook level. Now: 64-token blocks, each of the 4
// waves sweeps ALL 1024 k for its own 16-token m-tile -> the 4 waves request
// the SAME b lines within a short window (L1/L2 hits), unique-line traffic
// drops 4x (8.4 TB). bf16 A-fragments live in 32 regs/lane (built per level
// with the same RNE) so LDS stays ~72 KB -> 2 blocks/CU.
// launch_bounds(256,4) -> VGPR cap 128 (empirical: cap = 512/waves-per-SIMD).
// Decision arithmetic byte-identical to r14-r18 PASS (screen mapping, fkey
// atomicMin superset appends, np-exact rescore, lex (dist,k) min, residual
// chain). LCAP 24: overflow -> full exact scan (rare, correct).

#define NTOK 131072
#define DEPTH 8
#define KCB 1024
#define DIM 256
#define TM 64
#define RP 260
#define WWIN 0.12f
#define ALARM 0.05f
#define LCAP 24

typedef __attribute__((ext_vector_type(8))) short short8v;
typedef __attribute__((ext_vector_type(4))) float f32x4;

__device__ __forceinline__ unsigned short f32_to_bf16_rne(float f) {
  unsigned int u = __float_as_uint(f);
  return (unsigned short)((u + 0x7FFFu + ((u >> 16) & 1u)) >> 16);
}

__device__ __forceinline__ unsigned int fkey(float f) {
  unsigned int b = __float_as_uint(f);
  return (b & 0x80000000u) ? ~b : (b | 0x80000000u);
}
__device__ __forceinline__ float finv(unsigned int k) {
  return (k & 0x80000000u) ? __uint_as_float(k ^ 0x80000000u)
                           : __uint_as_float(~k);
}

__device__ __forceinline__ float np_sumsq_128(const float* p) {
  float s[16];
#pragma unroll
  for (int l = 0; l < 16; ++l) {
    float r0 = __fadd_rn(__fmul_rn(p[l], p[l]),
                         __fmul_rn(p[l + 64], p[l + 64]));
    float r1 = __fadd_rn(__fmul_rn(p[l + 16], p[l + 16]),
                         __fmul_rn(p[l + 80], p[l + 80]));
    float r2 = __fadd_rn(__fmul_rn(p[l + 32], p[l + 32]),
                         __fmul_rn(p[l + 96], p[l + 96]));
    float r3 = __fadd_rn(__fmul_rn(p[l + 48], p[l + 48]),
                         __fmul_rn(p[l + 112], p[l + 112]));
    s[l] = __fadd_rn(__fadd_rn(r0, r1), __fadd_rn(r2, r3));
  }
  float t[8];
#pragma unroll
  for (int l = 0; l < 8; ++l) t[l] = __fadd_rn(s[l], s[l + 8]);
  float u[4];
#pragma unroll
  for (int l = 0; l < 4; ++l) u[l] = __fadd_rn(t[l], t[l + 4]);
  return __fadd_rn(__fadd_rn(u[0], u[2]), __fadd_rn(u[1], u[3]));
}

__device__ __forceinline__ float np_sumsq_256(const float* p) {
  return __fadd_rn(np_sumsq_128(p), np_sumsq_128(p + 128));
}

// 16-lane-parallel replica of np_sumsq_256's exact add tree (r18-validated).
__device__ __forceinline__ float np_sumsq_256_par(const float* p, int kc) {
  float half[2];
#pragma unroll
  for (int h = 0; h < 2; ++h) {
    const float* q = p + h * 128;
    float r0 = __fadd_rn(__fmul_rn(q[kc], q[kc]),
                         __fmul_rn(q[kc + 64], q[kc + 64]));
    float r1 = __fadd_rn(__fmul_rn(q[kc + 16], q[kc + 16]),
                         __fmul_rn(q[kc + 80], q[kc + 80]));
    float r2 = __fadd_rn(__fmul_rn(q[kc + 32], q[kc + 32]),
                         __fmul_rn(q[kc + 96], q[kc + 96]));
    float r3 = __fadd_rn(__fmul_rn(q[kc + 48], q[kc + 48]),
                         __fmul_rn(q[kc + 112], q[kc + 112]));
    float s = __fadd_rn(__fadd_rn(r0, r1), __fadd_rn(r2, r3));
    float t = __fadd_rn(s, __shfl_down(s, 8, 16));
    float u = __fadd_rn(t, __shfl_down(t, 4, 16));
    float v = __fadd_rn(u, __shfl_down(u, 2, 16));
    half[h] = __fadd_rn(v, __shfl_down(v, 1, 16));
  }
  return __fadd_rn(half[0], half[1]);
}

__device__ __forceinline__ float np_dist(const float* rrow, const float* crow,
                                         float A, float C) {
  float dot = 0.f;
#pragma unroll 8
  for (int q = 0; q < 64; ++q) {
    float4 rv = *(const float4*)(rrow + q * 4);
    float4 cv = *(const float4*)(crow + q * 4);
    dot = fmaf(rv.x, cv.x, dot);
    dot = fmaf(rv.y, cv.y, dot);
    dot = fmaf(rv.z, cv.z, dot);
    dot = fmaf(rv.w, cv.w, dot);
  }
  return __fadd_rn(__fsub_rn(A, __fmul_rn(2.0f, dot)), C);
}

__global__ __launch_bounds__(256) void c2_kernel(const float* __restrict__ cbs,
                                                 float* __restrict__ C32g) {
  int gid = blockIdx.x * 256 + threadIdx.x;
  C32g[gid] = np_sumsq_256(cbs + (size_t)gid * DIM);
}

// cbf[(((lvl*64+g)*8+s)*64+lane)*8 + j] = bf16(cbs[lvl][g*16+(lane&15)]
//                                              [s*32+(lane>>4)*8+j])
__global__ __launch_bounds__(256) void pack_kernel(
    const float* __restrict__ cbs, unsigned short* __restrict__ cbf) {
  int gid = blockIdx.x * 256 + threadIdx.x;  // 262144
  int lane = gid & 63;
  int s = (gid >> 6) & 7;
  int g = (gid >> 9) & 63;
  int lvl = gid >> 15;
  int kcol = g * 16 + (lane & 15);
  int kd0 = s * 32 + (lane >> 4) * 8;
  const float* src = cbs + ((size_t)lvl * KCB + kcol) * DIM + kd0;
  unsigned short t[8];
#pragma unroll
  for (int j = 0; j < 8; ++j) t[j] = f32_to_bf16_rne(src[j]);
  ushort4 lo = {t[0], t[1], t[2], t[3]};
  ushort4 hi = {t[4], t[5], t[6], t[7]};
  *(ushort4*)(cbf + (size_t)gid * 8) = lo;
  *(ushort4*)(cbf + (size_t)gid * 8 + 4) = hi;
}

__global__ __launch_bounds__(256, 4) void rvq_kernel(
    const float* __restrict__ latent, const float* __restrict__ cbs,
    const float* __restrict__ C32g, const unsigned short* __restrict__ cbf,
    float* __restrict__ out) {
  __shared__ float r_m[TM][RP];  // 66.5 KB exact f32 residual
  __shared__ float A_s[TM];
  __shared__ unsigned int gkey[TM];
  __shared__ int cnt[TM];
  __shared__ int list[TM][LCAP];
  __shared__ int idx_s[TM];

  const int tid = threadIdx.x;
  const int w = tid >> 6;
  const int lane = tid & 63;
  const int lc = lane & 15;
  const int lg = lane >> 4;
  const int n0 = blockIdx.x * TM;
  const int mrow = w * 16 + lc;  // token whose A-row this lane supplies

  // ---- stage latent -> r_m (exact copy); init gkey/cnt ----
  {
    int tok = tid >> 2;
    int part = tid & 3;
    const float* src = latent + (size_t)(n0 + tok) * DIM + part * 64;
#pragma unroll
    for (int j = 0; j < 16; ++j)
      *(float4*)&r_m[tok][part * 64 + j * 4] = *(const float4*)(src + j * 4);
    if (tid < TM) {
      gkey[tid] = 0xFFFFFFFFu;
      cnt[tid] = 0;
    }
  }
  __syncthreads();

  for (int lvl = 0; lvl < DEPTH; ++lvl) {
    const float* cb = cbs + (size_t)lvl * KCB * DIM;

    // exact A per token (np tree), 16 lanes/token, 4 sweeps
#pragma unroll
    for (int tb = 0; tb < 4; ++tb) {
      int t = tb * 16 + (tid >> 4);
      float A = np_sumsq_256_par(&r_m[t][0], tid & 15);
      if ((tid & 15) == 0) A_s[t] = A;
    }

    // build A-fragments in registers (same RNE, same layout as rb was)
    short8v afr[8];
#pragma unroll
    for (int s = 0; s < 8; ++s) {
      unsigned short tmp[8];
#pragma unroll
      for (int j = 0; j < 8; ++j)
        tmp[j] = f32_to_bf16_rne(r_m[mrow][s * 32 + lg * 8 + j]);
      afr[s] = (short8v){(short)tmp[0], (short)tmp[1], (short)tmp[2],
                         (short)tmp[3], (short)tmp[4], (short)tmp[5],
                         (short)tmp[6], (short)tmp[7]};
    }

    // ---- screen: every wave sweeps ALL 64 k-tiles for its m-tile ----
    // addr(shorts): lvl*262144 + g*4096 + s*512 + lane*8
    const unsigned short* bp = cbf + (size_t)lvl * 262144 + lane * 8;
    f32x4 acc[4];
#pragma unroll
    for (int nt = 0; nt < 4; ++nt) acc[nt] = (f32x4){0.f, 0.f, 0.f, 0.f};
    short8v b0c = *(const short8v*)(bp + 0 * 4096);
    short8v b1c = *(const short8v*)(bp + 1 * 4096);
    short8v b2c = *(const short8v*)(bp + 2 * 4096);
    short8v b3c = *(const short8v*)(bp + 3 * 4096);

#pragma unroll 1
    for (int pass = 0; pass < 16; ++pass) {
#pragma unroll
      for (int s = 0; s < 8; ++s) {
        short8v b0n, b1n, b2n, b3n;
        const bool pf = (s < 7) || (pass < 15);
        if (pf) {
          const unsigned short* bn =
              (s < 7) ? (bp + (s + 1) * 512) : (bp + 16384);
          b0n = *(const short8v*)(bn + 0 * 4096);
          b1n = *(const short8v*)(bn + 1 * 4096);
          b2n = *(const short8v*)(bn + 2 * 4096);
          b3n = *(const short8v*)(bn + 3 * 4096);
        }
        acc[0] =
            __builtin_amdgcn_mfma_f32_16x16x32_bf16(afr[s], b0c, acc[0], 0, 0, 0);
        acc[1] =
            __builtin_amdgcn_mfma_f32_16x16x32_bf16(afr[s], b1c, acc[1], 0, 0, 0);
        acc[2] =
            __builtin_amdgcn_mfma_f32_16x16x32_bf16(afr[s], b2c, acc[2], 0, 0, 0);
        acc[3] =
            __builtin_amdgcn_mfma_f32_16x16x32_bf16(afr[s], b3c, acc[3], 0, 0, 0);
        if (pf) {
          b0c = b0n;
          b1c = b1n;
          b2c = b2n;
          b3c = b3n;
        }
      }

      // transform to s~ = C - 2*dot; per-token mins; superset append
      float tmin[4];
#pragma unroll
      for (int reg = 0; reg < 4; ++reg) tmin[reg] = 3.4e38f;
#pragma unroll
      for (int nt = 0; nt < 4; ++nt) {
        float Cv = C32g[lvl * KCB + (pass * 4 + nt) * 16 + lc];
        f32x4 sc;
#pragma unroll
        for (int reg = 0; reg < 4; ++reg) {
          float v = __fsub_rn(Cv, __fmul_rn(2.0f, acc[nt][reg]));
          sc[reg] = v;
          tmin[reg] = fminf(tmin[reg], v);
        }
        acc[nt] = sc;
      }
#pragma unroll
      for (int m = 1; m <= 8; m <<= 1)
#pragma unroll
        for (int reg = 0; reg < 4; ++reg)
          tmin[reg] = fminf(tmin[reg], __shfl_xor(tmin[reg], m));
      if (lc == 0) {
#pragma unroll
        for (int reg = 0; reg < 4; ++reg)
          atomicMin(&gkey[w * 16 + lg * 4 + reg], fkey(tmin[reg]));
      }
#pragma unroll
      for (int reg = 0; reg < 4; ++reg) {
        int t = w * 16 + lg * 4 + reg;
        float th = finv(gkey[t]) + WWIN;
#pragma unroll
        for (int nt = 0; nt < 4; ++nt) {
          if (acc[nt][reg] <= th) {
            int slot = atomicAdd(&cnt[t], 1);
            if (slot < LCAP) list[t][slot] = (pass * 4 + nt) * 16 + lc;
          }
        }
      }
#pragma unroll
      for (int nt = 0; nt < 4; ++nt) acc[nt] = (f32x4){0.f, 0.f, 0.f, 0.f};
      bp += 16384;
    }
    __syncthreads();  // lists, gkey, A_s final

    // ---- np-exact rescore (16 threads per token, 4 sweeps) ----
#pragma unroll 1
    for (int tb = 0; tb < 4; ++tb) {
      int t = tb * 16 + (tid >> 4);
      int kc = tid & 15;
      float A = A_s[t];
      float gminf = finv(gkey[t]);
      int n = cnt[t];
      float bd = 3.4e38f;
      int bk = KCB;
      if (n <= LCAP) {
        for (int ci = kc; ci < n; ci += 16) {
          int k = list[t][ci];
          float d = np_dist(&r_m[t][0], cb + (size_t)k * DIM, A,
                            C32g[lvl * KCB + k]);
          if (d < bd || (d == bd && k < bk)) {
            bd = d;
            bk = k;
          }
        }
      }
#pragma unroll
      for (int m = 1; m <= 8; m <<= 1) {
        float od = __shfl_xor(bd, m);
        int ok = __shfl_xor(bk, m);
        if (od < bd || (od == bd && ok < bk)) {
          bd = od;
          bk = ok;
        }
      }
      bool redo =
          (n > LCAP) || (fabsf(__fsub_rn(bd, A) - gminf) > (WWIN - ALARM));
      if (redo) {
        bd = 3.4e38f;
        bk = KCB;
        for (int k = kc; k < KCB; k += 16) {
          float d = np_dist(&r_m[t][0], cb + (size_t)k * DIM, A,
                            C32g[lvl * KCB + k]);
          if (d < bd || (d == bd && k < bk)) {
            bd = d;
            bk = k;
          }
        }
#pragma unroll
        for (int m = 1; m <= 8; m <<= 1) {
          float od = __shfl_xor(bd, m);
          int ok = __shfl_xor(bk, m);
          if (od < bd || (od == bd && ok < bk)) {
            bd = od;
            bk = ok;
          }
        }
      }
      if (kc == 0) {
        idx_s[t] = bk;
        out[(size_t)NTOK * DIM + (size_t)lvl * NTOK + n0 + t] = (float)bk;
      }
    }
    __syncthreads();

    // ---- residual update r = fl(r - c[idx]); reset gkey/cnt ----
#pragma unroll
    for (int tb = 0; tb < 4; ++tb) {
      int tok = tb * 16 + (tid >> 4);
      int db = (tid & 15) * 16;
      const float* crow = cb + (size_t)idx_s[tok] * DIM + db;
#pragma unroll
      for (int j = 0; j < 4; ++j) {
        float4 cv4 = *(const float4*)(crow + j * 4);
        int d = db + j * 4;
        r_m[tok][d + 0] = __fsub_rn(r_m[tok][d + 0], cv4.x);
        r_m[tok][d + 1] = __fsub_rn(r_m[tok][d + 1], cv4.y);
        r_m[tok][d + 2] = __fsub_rn(r_m[tok][d + 2], cv4.z);
        r_m[tok][d + 3] = __fsub_rn(r_m[tok][d + 3], cv4.w);
      }
    }
    if (tid < TM) {
      gkey[tid] = 0xFFFFFFFFu;
      cnt[tid] = 0;
    }
    __syncthreads();
  }

  // ---- straight_through = fl(l + fl(q - l)), q = fl(l - r) ----
  {
    int tok = tid >> 2;
    int part = tid & 3;
#pragma unroll
    for (int j = 0; j < 16; ++j) {
      int d = part * 64 + j * 4;
      size_t gi = (size_t)(n0 + tok) * DIM + d;
      float4 l4 = *(const float4*)(latent + gi);
      float4 qv;
      float q;
      q = __fsub_rn(l4.x, r_m[tok][d + 0]);
      qv.x = __fadd_rn(l4.x, __fsub_rn(q, l4.x));
      q = __fsub_rn(l4.y, r_m[tok][d + 1]);
      qv.y = __fadd_rn(l4.y, __fsub_rn(q, l4.y));
      q = __fsub_rn(l4.z, r_m[tok][d + 2]);
      qv.z = __fadd_rn(l4.z, __fsub_rn(q, l4.z));
      q = __fsub_rn(l4.w, r_m[tok][d + 3]);
      qv.w = __fadd_rn(l4.w, __fsub_rn(q, l4.w));
      *(float4*)(out + gi) = qv;
    }
  }
}

extern "C" void kernel_launch(void* const* d_in, const int* in_sizes, int n_in,
                              void* d_out, int out_size, void* d_ws,
                              size_t ws_size, hipStream_t stream) {
  const float* latent = (const float*)d_in[0];
  const float* codebooks = (const float*)d_in[1];
  float* out = (float*)d_out;
  float* C32g = (float*)d_ws;                                    // 32 KB
  unsigned short* cbf = (unsigned short*)((char*)d_ws + 32768);  // 4 MB

  hipLaunchKernelGGL(c2_kernel, dim3(DEPTH * KCB / 256), dim3(256), 0, stream,
                     codebooks, C32g);
  hipLaunchKernelGGL(pack_kernel, dim3(DEPTH * 64 * 8 * 64 / 256), dim3(256),
                     0, stream, codebooks, cbf);
  hipLaunchKernelGGL(rvq_kernel, dim3(NTOK / TM), dim3(256), 0, stream, latent,
                     codebooks, C32g, cbf, out);
}

// Round 20
// 1986.504 us; speedup vs baseline: 1.4753x; 1.4753x over previous
//
#include <hip/hip_runtime.h>

// Residual VQ — bf16-MFMA screen + np-exact rescore. Round 20: r18 structure
// with TM=32 (each wave adds a SECOND m-tile over the same 16-k-tile range).
// r19 falsified the traffic theory: latency-event count per wave binds.
// Here: same 128 b-loads/wave/level as r18, but 8 MFMA of cover per s-iter
// (2x) and half the L2 traffic per token. VGPR ~115 -> (256,4) cap 128 ->
// 2 blocks/CU (8 waves). Decision arithmetic byte-identical to r14-r19 PASS.

#define NTOK 131072
#define DEPTH 8
#define KCB 1024
#define DIM 256
#define TM 32
#define RP 260
#define RBP 264
#define WWIN 0.12f
#define ALARM 0.05f
#define LCAP 64

typedef __attribute__((ext_vector_type(8))) short short8v;
typedef __attribute__((ext_vector_type(4))) float f32x4;

__device__ __forceinline__ unsigned short f32_to_bf16_rne(float f) {
  unsigned int u = __float_as_uint(f);
  return (unsigned short)((u + 0x7FFFu + ((u >> 16) & 1u)) >> 16);
}

__device__ __forceinline__ unsigned int fkey(float f) {
  unsigned int b = __float_as_uint(f);
  return (b & 0x80000000u) ? ~b : (b | 0x80000000u);
}
__device__ __forceinline__ float finv(unsigned int k) {
  return (k & 0x80000000u) ? __uint_as_float(k ^ 0x80000000u)
                           : __uint_as_float(~k);
}

__device__ __forceinline__ float np_sumsq_128(const float* p) {
  float s[16];
#pragma unroll
  for (int l = 0; l < 16; ++l) {
    float r0 = __fadd_rn(__fmul_rn(p[l], p[l]),
                         __fmul_rn(p[l + 64], p[l + 64]));
    float r1 = __fadd_rn(__fmul_rn(p[l + 16], p[l + 16]),
                         __fmul_rn(p[l + 80], p[l + 80]));
    float r2 = __fadd_rn(__fmul_rn(p[l + 32], p[l + 32]),
                         __fmul_rn(p[l + 96], p[l + 96]));
    float r3 = __fadd_rn(__fmul_rn(p[l + 48], p[l + 48]),
                         __fmul_rn(p[l + 112], p[l + 112]));
    s[l] = __fadd_rn(__fadd_rn(r0, r1), __fadd_rn(r2, r3));
  }
  float t[8];
#pragma unroll
  for (int l = 0; l < 8; ++l) t[l] = __fadd_rn(s[l], s[l + 8]);
  float u[4];
#pragma unroll
  for (int l = 0; l < 4; ++l) u[l] = __fadd_rn(t[l], t[l + 4]);
  return __fadd_rn(__fadd_rn(u[0], u[2]), __fadd_rn(u[1], u[3]));
}

__device__ __forceinline__ float np_sumsq_256(const float* p) {
  return __fadd_rn(np_sumsq_128(p), np_sumsq_128(p + 128));
}

// 16-lane-parallel replica of np_sumsq_256's exact add tree (r18-validated).
__device__ __forceinline__ float np_sumsq_256_par(const float* p, int kc) {
  float half[2];
#pragma unroll
  for (int h = 0; h < 2; ++h) {
    const float* q = p + h * 128;
    float r0 = __fadd_rn(__fmul_rn(q[kc], q[kc]),
                         __fmul_rn(q[kc + 64], q[kc + 64]));
    float r1 = __fadd_rn(__fmul_rn(q[kc + 16], q[kc + 16]),
                         __fmul_rn(q[kc + 80], q[kc + 80]));
    float r2 = __fadd_rn(__fmul_rn(q[kc + 32], q[kc + 32]),
                         __fmul_rn(q[kc + 96], q[kc + 96]));
    float r3 = __fadd_rn(__fmul_rn(q[kc + 48], q[kc + 48]),
                         __fmul_rn(q[kc + 112], q[kc + 112]));
    float s = __fadd_rn(__fadd_rn(r0, r1), __fadd_rn(r2, r3));
    float t = __fadd_rn(s, __shfl_down(s, 8, 16));
    float u = __fadd_rn(t, __shfl_down(t, 4, 16));
    float v = __fadd_rn(u, __shfl_down(u, 2, 16));
    half[h] = __fadd_rn(v, __shfl_down(v, 1, 16));
  }
  return __fadd_rn(half[0], half[1]);
}

__device__ __forceinline__ float np_dist(const float* rrow, const float* crow,
                                         float A, float C) {
  float dot = 0.f;
#pragma unroll 8
  for (int q = 0; q < 64; ++q) {
    float4 rv = *(const float4*)(rrow + q * 4);
    float4 cv = *(const float4*)(crow + q * 4);
    dot = fmaf(rv.x, cv.x, dot);
    dot = fmaf(rv.y, cv.y, dot);
    dot = fmaf(rv.z, cv.z, dot);
    dot = fmaf(rv.w, cv.w, dot);
  }
  return __fadd_rn(__fsub_rn(A, __fmul_rn(2.0f, dot)), C);
}

__global__ __launch_bounds__(256) void c2_kernel(const float* __restrict__ cbs,
                                                 float* __restrict__ C32g) {
  int gid = blockIdx.x * 256 + threadIdx.x;
  C32g[gid] = np_sumsq_256(cbs + (size_t)gid * DIM);
}

// cbf[(((lvl*64+g)*8+s)*64+lane)*8 + j] = bf16(cbs[lvl][g*16+(lane&15)]
//                                              [s*32+(lane>>4)*8+j])
__global__ __launch_bounds__(256) void pack_kernel(
    const float* __restrict__ cbs, unsigned short* __restrict__ cbf) {
  int gid = blockIdx.x * 256 + threadIdx.x;  // 262144
  int lane = gid & 63;
  int s = (gid >> 6) & 7;
  int g = (gid >> 9) & 63;
  int lvl = gid >> 15;
  int kcol = g * 16 + (lane & 15);
  int kd0 = s * 32 + (lane >> 4) * 8;
  const float* src = cbs + ((size_t)lvl * KCB + kcol) * DIM + kd0;
  unsigned short t[8];
#pragma unroll
  for (int j = 0; j < 8; ++j) t[j] = f32_to_bf16_rne(src[j]);
  ushort4 lo = {t[0], t[1], t[2], t[3]};
  ushort4 hi = {t[4], t[5], t[6], t[7]};
  *(ushort4*)(cbf + (size_t)gid * 8) = lo;
  *(ushort4*)(cbf + (size_t)gid * 8 + 4) = hi;
}

__global__ __launch_bounds__(256, 4) void rvq_kernel(
    const float* __restrict__ latent, const float* __restrict__ cbs,
    const float* __restrict__ C32g, const unsigned short* __restrict__ cbf,
    float* __restrict__ out) {
  __shared__ float r_m[TM][RP];                          // 33.3 KB
  __shared__ __align__(16) unsigned short rb[TM * RBP];  // 16.9 KB
  __shared__ float A_s[TM];
  __shared__ unsigned int gkey[TM];
  __shared__ int cnt[TM];
  __shared__ int list[TM][LCAP];
  __shared__ int idx_s[TM];

  const int tid = threadIdx.x;
  const int w = tid >> 6;
  const int lane = tid & 63;
  const int lc = lane & 15;
  const int lg = lane >> 4;
  const int n0 = blockIdx.x * TM;

  // ---- stage latent -> r_m (exact) + rb (bf16); init gkey/cnt ----
  {
    int tok = tid >> 3;          // 0..31
    int db = (tid & 7) * 32;
#pragma unroll
    for (int j = 0; j < 8; ++j) {
      float4 v = *(const float4*)(latent + (size_t)(n0 + tok) * DIM + db + j * 4);
      *(float4*)&r_m[tok][db + j * 4] = v;
      rb[tok * RBP + db + j * 4 + 0] = f32_to_bf16_rne(v.x);
      rb[tok * RBP + db + j * 4 + 1] = f32_to_bf16_rne(v.y);
      rb[tok * RBP + db + j * 4 + 2] = f32_to_bf16_rne(v.z);
      rb[tok * RBP + db + j * 4 + 3] = f32_to_bf16_rne(v.w);
    }
    if (tid < TM) {
      gkey[tid] = 0xFFFFFFFFu;
      cnt[tid] = 0;
    }
  }
  __syncthreads();

  for (int lvl = 0; lvl < DEPTH; ++lvl) {
    const float* cb = cbs + (size_t)lvl * KCB * DIM;

    // exact A per token (np tree), 16 lanes/token, 2 sweeps
#pragma unroll
    for (int tb = 0; tb < 2; ++tb) {
      int t = tb * 16 + (tid >> 4);
      float A = np_sumsq_256_par(&r_m[t][0], tid & 15);
      if ((tid & 15) == 0) A_s[t] = A;
    }

    // ---- 4 screen passes, barrier-free (atomicMin gkey, superset appends)
#pragma unroll 1
    for (int p = 0; p < 4; ++p) {
      f32x4 acc[2][4];
#pragma unroll
      for (int mt = 0; mt < 2; ++mt)
#pragma unroll
        for (int nt = 0; nt < 4; ++nt) acc[mt][nt] = (f32x4){0.f, 0.f, 0.f, 0.f};

      const int kt0 = w * 16 + p * 4;  // wave-contiguous 4 k-tiles
      const unsigned short* bp0 =
          cbf + ((((size_t)lvl * 64 + kt0) * 8) * 64 + lane) * 8;
      short8v a0c = *(const short8v*)&rb[lc * RBP + lg * 8];
      short8v a1c = *(const short8v*)&rb[(16 + lc) * RBP + lg * 8];
      short8v b0c = *(const short8v*)(bp0 + 0 * 4096);
      short8v b1c = *(const short8v*)(bp0 + 1 * 4096);
      short8v b2c = *(const short8v*)(bp0 + 2 * 4096);
      short8v b3c = *(const short8v*)(bp0 + 3 * 4096);
#pragma unroll
      for (int s = 0; s < 8; ++s) {
        short8v a0n, a1n, b0n, b1n, b2n, b3n;
        if (s < 7) {  // issue next s-iter's loads before current MFMAs
          a0n = *(const short8v*)&rb[lc * RBP + (s + 1) * 32 + lg * 8];
          a1n = *(const short8v*)&rb[(16 + lc) * RBP + (s + 1) * 32 + lg * 8];
          const unsigned short* bs = bp0 + (size_t)(s + 1) * 512;
          b0n = *(const short8v*)(bs + 0 * 4096);
          b1n = *(const short8v*)(bs + 1 * 4096);
          b2n = *(const short8v*)(bs + 2 * 4096);
          b3n = *(const short8v*)(bs + 3 * 4096);
        }
        acc[0][0] = __builtin_amdgcn_mfma_f32_16x16x32_bf16(a0c, b0c, acc[0][0], 0, 0, 0);
        acc[0][1] = __builtin_amdgcn_mfma_f32_16x16x32_bf16(a0c, b1c, acc[0][1], 0, 0, 0);
        acc[0][2] = __builtin_amdgcn_mfma_f32_16x16x32_bf16(a0c, b2c, acc[0][2], 0, 0, 0);
        acc[0][3] = __builtin_amdgcn_mfma_f32_16x16x32_bf16(a0c, b3c, acc[0][3], 0, 0, 0);
        acc[1][0] = __builtin_amdgcn_mfma_f32_16x16x32_bf16(a1c, b0c, acc[1][0], 0, 0, 0);
        acc[1][1] = __builtin_amdgcn_mfma_f32_16x16x32_bf16(a1c, b1c, acc[1][1], 0, 0, 0);
        acc[1][2] = __builtin_amdgcn_mfma_f32_16x16x32_bf16(a1c, b2c, acc[1][2], 0, 0, 0);
        acc[1][3] = __builtin_amdgcn_mfma_f32_16x16x32_bf16(a1c, b3c, acc[1][3], 0, 0, 0);
        if (s < 7) {
          a0c = a0n;
          a1c = a1n;
          b0c = b0n;
          b1c = b1n;
          b2c = b2n;
          b3c = b3n;
        }
      }

      // transform to s~ = C - 2*dot; per-token mins
      float tmin[2][4];
#pragma unroll
      for (int mt = 0; mt < 2; ++mt)
#pragma unroll
        for (int reg = 0; reg < 4; ++reg) tmin[mt][reg] = 3.4e38f;
#pragma unroll
      for (int nt = 0; nt < 4; ++nt) {
        float Cv = C32g[lvl * KCB + (kt0 + nt) * 16 + lc];
#pragma unroll
        for (int mt = 0; mt < 2; ++mt) {
          f32x4 sc;
#pragma unroll
          for (int reg = 0; reg < 4; ++reg) {
            float v = __fsub_rn(Cv, __fmul_rn(2.0f, acc[mt][nt][reg]));
            sc[reg] = v;
            tmin[mt][reg] = fminf(tmin[mt][reg], v);
          }
          acc[mt][nt] = sc;
        }
      }
#pragma unroll
      for (int m = 1; m <= 8; m <<= 1)
#pragma unroll
        for (int mt = 0; mt < 2; ++mt)
#pragma unroll
          for (int reg = 0; reg < 4; ++reg)
            tmin[mt][reg] = fminf(tmin[mt][reg], __shfl_xor(tmin[mt][reg], m));
      if (lc == 0) {
#pragma unroll
        for (int mt = 0; mt < 2; ++mt)
#pragma unroll
          for (int reg = 0; reg < 4; ++reg)
            atomicMin(&gkey[mt * 16 + lg * 4 + reg], fkey(tmin[mt][reg]));
      }
      // append vs current gmin (>= final => superset admission, safe)
#pragma unroll
      for (int mt = 0; mt < 2; ++mt)
#pragma unroll
        for (int reg = 0; reg < 4; ++reg) {
          int t = mt * 16 + lg * 4 + reg;
          float th = finv(gkey[t]) + WWIN;
#pragma unroll
          for (int nt = 0; nt < 4; ++nt) {
            if (acc[mt][nt][reg] <= th) {
              int slot = atomicAdd(&cnt[t], 1);
              if (slot < LCAP) list[t][slot] = (kt0 + nt) * 16 + lc;
            }
          }
        }
    }
    __syncthreads();  // lists, gkey, A_s final

    // ---- np-exact rescore (16 threads per token, 2 sweeps) ----
#pragma unroll 1
    for (int tb = 0; tb < 2; ++tb) {
      int t = tb * 16 + (tid >> 4);
      int kc = tid & 15;
      float A = A_s[t];
      float gminf = finv(gkey[t]);
      int n = cnt[t];
      float bd = 3.4e38f;
      int bk = KCB;
      if (n <= LCAP) {
        for (int ci = kc; ci < n; ci += 16) {
          int k = list[t][ci];
          float d = np_dist(&r_m[t][0], cb + (size_t)k * DIM, A,
                            C32g[lvl * KCB + k]);
          if (d < bd || (d == bd && k < bk)) {
            bd = d;
            bk = k;
          }
        }
      }
#pragma unroll
      for (int m = 1; m <= 8; m <<= 1) {
        float od = __shfl_xor(bd, m);
        int ok = __shfl_xor(bk, m);
        if (od < bd || (od == bd && ok < bk)) {
          bd = od;
          bk = ok;
        }
      }
      bool redo =
          (n > LCAP) || (fabsf(__fsub_rn(bd, A) - gminf) > (WWIN - ALARM));
      if (redo) {
        bd = 3.4e38f;
        bk = KCB;
        for (int k = kc; k < KCB; k += 16) {
          float d = np_dist(&r_m[t][0], cb + (size_t)k * DIM, A,
                            C32g[lvl * KCB + k]);
          if (d < bd || (d == bd && k < bk)) {
            bd = d;
            bk = k;
          }
        }
#pragma unroll
        for (int m = 1; m <= 8; m <<= 1) {
          float od = __shfl_xor(bd, m);
          int ok = __shfl_xor(bk, m);
          if (od < bd || (od == bd && ok < bk)) {
            bd = od;
            bk = ok;
          }
        }
      }
      if (kc == 0) {
        idx_s[t] = bk;
        out[(size_t)NTOK * DIM + (size_t)lvl * NTOK + n0 + t] = (float)bk;
      }
    }
    __syncthreads();

    // ---- residual update (exact) + rb refresh + next-level inits ----
    {
      int tok = tid >> 3;
      int db = (tid & 7) * 32;
      const float* crow = cb + (size_t)idx_s[tok] * DIM + db;
#pragma unroll
      for (int j = 0; j < 8; ++j) {
        float4 cv4 = *(const float4*)(crow + j * 4);
        int d = db + j * 4;
        float x0 = __fsub_rn(r_m[tok][d + 0], cv4.x);
        float x1 = __fsub_rn(r_m[tok][d + 1], cv4.y);
        float x2 = __fsub_rn(r_m[tok][d + 2], cv4.z);
        float x3 = __fsub_rn(r_m[tok][d + 3], cv4.w);
        r_m[tok][d + 0] = x0;
        r_m[tok][d + 1] = x1;
        r_m[tok][d + 2] = x2;
        r_m[tok][d + 3] = x3;
        rb[tok * RBP + d + 0] = f32_to_bf16_rne(x0);
        rb[tok * RBP + d + 1] = f32_to_bf16_rne(x1);
        rb[tok * RBP + d + 2] = f32_to_bf16_rne(x2);
        rb[tok * RBP + d + 3] = f32_to_bf16_rne(x3);
      }
      if (tid < TM) {
        gkey[tid] = 0xFFFFFFFFu;
        cnt[tid] = 0;
      }
    }
    __syncthreads();
  }

  // ---- straight_through = fl(l + fl(q - l)), q = fl(l - r) ----
  {
    int tok = tid >> 3;
    int db = (tid & 7) * 32;
#pragma unroll
    for (int j = 0; j < 8; ++j) {
      int d = db + j * 4;
      size_t gi = (size_t)(n0 + tok) * DIM + d;
      float4 l4 = *(const float4*)(latent + gi);
      float4 qv;
      float q;
      q = __fsub_rn(l4.x, r_m[tok][d + 0]);
      qv.x = __fadd_rn(l4.x, __fsub_rn(q, l4.x));
      q = __fsub_rn(l4.y, r_m[tok][d + 1]);
      qv.y = __fadd_rn(l4.y, __fsub_rn(q, l4.y));
      q = __fsub_rn(l4.z, r_m[tok][d + 2]);
      qv.z = __fadd_rn(l4.z, __fsub_rn(q, l4.z));
      q = __fsub_rn(l4.w, r_m[tok][d + 3]);
      qv.w = __fadd_rn(l4.w, __fsub_rn(q, l4.w));
      *(float4*)(out + gi) = qv;
    }
  }
}

extern "C" void kernel_launch(void* const* d_in, const int* in_sizes, int n_in,
                              void* d_out, int out_size, void* d_ws,
                              size_t ws_size, hipStream_t stream) {
  const float* latent = (const float*)d_in[0];
  const float* codebooks = (const float*)d_in[1];
  float* out = (float*)d_out;
  float* C32g = (float*)d_ws;                                    // 32 KB
  unsigned short* cbf = (unsigned short*)((char*)d_ws + 32768);  // 4 MB

  hipLaunchKernelGGL(c2_kernel, dim3(DEPTH * KCB / 256), dim3(256), 0, stream,
                     codebooks, C32g);
  hipLaunchKernelGGL(pack_kernel, dim3(DEPTH * 64 * 8 * 64 / 256), dim3(256),
                     0, stream, codebooks, cbf);
  hipLaunchKernelGGL(rvq_kernel, dim3(NTOK / TM), dim3(256), 0, stream, latent,
                     codebooks, C32g, cbf, out);
}